// Round 1
// baseline (1039.021 us; speedup 1.0000x reference)
//
#include <hip/hip_runtime.h>
#include <hip/hip_bf16.h>
#include <cstdint>
#include <cstddef>

using bf16 = __hip_bfloat16;
typedef __attribute__((ext_vector_type(8))) short bf16x8;  // 8 bf16 (4 VGPRs)
typedef __attribute__((ext_vector_type(4))) float f32x4;

static constexpr int B_ = 2, S_ = 1024, D_ = 512, H_ = 8;
static constexpr int M_ = B_ * S_;     // 2048 rows
static constexpr float EPS_ = 1e-6f;

__device__ __forceinline__ float sigmoidf_(float x) { return 1.0f / (1.0f + __expf(-x)); }

// ---------------- transpose + cast: W [K][N] f32 -> Wt [N][K] bf16 ----------------
__global__ __launch_bounds__(256) void k_transpose_cast(const float* __restrict__ W,
                                                        bf16* __restrict__ Wt, int K, int N) {
  __shared__ float tile[32][33];
  int n0 = blockIdx.x * 32, k0 = blockIdx.y * 32;
  int tx = threadIdx.x, ty = threadIdx.y;  // 32 x 8
#pragma unroll
  for (int r = ty; r < 32; r += 8) tile[r][tx] = W[(size_t)(k0 + r) * N + n0 + tx];
  __syncthreads();
#pragma unroll
  for (int r = ty; r < 32; r += 8)
    Wt[(size_t)(n0 + r) * K + k0 + tx] = __float2bfloat16(tile[tx][r]);
}

// ---------------- rmsnorm over D=512, optional f32 + bf16 outputs ----------------
__global__ __launch_bounds__(256) void k_rmsnorm(const float* __restrict__ x,
                                                 const float* __restrict__ scale,
                                                 float* __restrict__ outf,
                                                 bf16* __restrict__ outb) {
  int m = blockIdx.x, tid = threadIdx.x;
  const float* row = x + (size_t)m * D_;
  float2 v = *(const float2*)(row + tid * 2);
  float ss = v.x * v.x + v.y * v.y;
#pragma unroll
  for (int o = 1; o < 64; o <<= 1) ss += __shfl_xor(ss, o);
  __shared__ float wsum[4];
  if ((tid & 63) == 0) wsum[tid >> 6] = ss;
  __syncthreads();
  float tot = wsum[0] + wsum[1] + wsum[2] + wsum[3];
  float rs = rsqrtf(tot * (1.0f / (float)D_) + EPS_);
  float2 sc = *(const float2*)(scale + tid * 2);
  float o0 = v.x * rs * sc.x, o1 = v.y * rs * sc.y;
  if (outf) {
    float2 o; o.x = o0; o.y = o1;
    *(float2*)(outf + (size_t)m * D_ + tid * 2) = o;
  }
  if (outb) {
    bf16* p = outb + (size_t)m * D_ + tid * 2;
    p[0] = __float2bfloat16(o0); p[1] = __float2bfloat16(o1);
  }
}

// ---------------- action-embedding gather ----------------
__global__ __launch_bounds__(256) void k_gather(const int* __restrict__ action,
                                                const float* __restrict__ embed,
                                                float* __restrict__ aef, bf16* __restrict__ aeb) {
  int m = blockIdx.x, tid = threadIdx.x;
  int a = action[m];
  float2 v = *(const float2*)(embed + (size_t)a * 512 + tid * 2);
  *(float2*)(aef + (size_t)m * 512 + tid * 2) = v;
  bf16* p = aeb + (size_t)m * 512 + tid * 2;
  p[0] = __float2bfloat16(v.x); p[1] = __float2bfloat16(v.y);
}

// ---------------- [2048,512] @ [512,8] -> sigmoid -> [2048,8] ----------------
__global__ __launch_bounds__(256) void k_dot8_sigmoid(const float* __restrict__ X,
                                                      const float* __restrict__ W8,
                                                      float* __restrict__ out) {
  int m = blockIdx.x, tid = threadIdx.x;
  float x0 = X[(size_t)m * D_ + tid];
  float x1 = X[(size_t)m * D_ + 256 + tid];
  float p[8];
#pragma unroll
  for (int j = 0; j < 8; ++j)
    p[j] = x0 * W8[tid * 8 + j] + x1 * W8[(tid + 256) * 8 + j];
#pragma unroll
  for (int j = 0; j < 8; ++j) {
#pragma unroll
    for (int o = 1; o < 64; o <<= 1) p[j] += __shfl_xor(p[j], o);
  }
  __shared__ float sacc[4][8];
  if ((tid & 63) == 0) {
#pragma unroll
    for (int j = 0; j < 8; ++j) sacc[tid >> 6][j] = p[j];
  }
  __syncthreads();
  if (tid < 8) {
    float s = sacc[0][tid] + sacc[1][tid] + sacc[2][tid] + sacc[3][tid];
    out[(size_t)m * 8 + tid] = sigmoidf_(s);
  }
}

// ---------------- per (m,h): L2-normalize q,k in place; dots kq, kbv, bvq ----------------
__global__ __launch_bounds__(64) void k_qknorm_dots(float* __restrict__ qkv,
                                                    const float* __restrict__ buv,
                                                    float* __restrict__ kqd,
                                                    float* __restrict__ kbvd,
                                                    float* __restrict__ bvqd) {
  int blk = blockIdx.x;
  int m = blk >> 3, h = blk & 7, t = threadIdx.x;
  size_t qi = (size_t)m * 1536 + h * 64 + t;
  float q = qkv[qi], k = qkv[qi + 512];
  float bv = buv[(size_t)m * 1024 + 512 + h * 64 + t];
  float qs = q * q, ks = k * k;
#pragma unroll
  for (int o = 1; o < 64; o <<= 1) { qs += __shfl_xor(qs, o); ks += __shfl_xor(ks, o); }
  float qn = q / (sqrtf(qs) + EPS_);
  float kn = k / (sqrtf(ks) + EPS_);
  qkv[qi] = qn; qkv[qi + 512] = kn;
  float d0 = kn * qn, d1 = kn * bv, d2 = bv * qn;
#pragma unroll
  for (int o = 1; o < 64; o <<= 1) {
    d0 += __shfl_xor(d0, o); d1 += __shfl_xor(d1, o); d2 += __shfl_xor(d2, o);
  }
  if (t == 0) {
    kqd[(size_t)m * 8 + h] = d0; kbvd[(size_t)m * 8 + h] = d1; bvqd[(size_t)m * 8 + h] = d2;
  }
}

// ---------------- bf16 MFMA GEMM: C[M,N] = epi(A[M,K] @ Bt[N,K]^T) ----------------
// EPI: 0 none, 1 silu if col<actSplit, 2 +bias[col]+res, 3 +res
template <int EPI, int WNF>
__global__ __launch_bounds__(256) void k_gemm(const bf16* __restrict__ A,
                                              const bf16* __restrict__ Bt,
                                              float* __restrict__ C, int M, int N, int K,
                                              int actSplit, const float* __restrict__ bias,
                                              const float* __restrict__ res) {
  constexpr int TN = WNF * 32;  // 128 or 64
  __shared__ bf16 As[128][40];  // padded rows: 80B stride -> ~2-way banked (free)
  __shared__ bf16 Bs[TN][40];
  const int tid = threadIdx.x;
  const int wave = tid >> 6, lane = tid & 63;
  const int wm = wave >> 1, wn = wave & 1;
  const int m0 = blockIdx.y * 128, n0 = blockIdx.x * TN;
  const int lrow = lane & 15, lk = (lane >> 4) * 8;

  f32x4 acc[4][WNF];
#pragma unroll
  for (int i = 0; i < 4; ++i)
#pragma unroll
    for (int j = 0; j < WNF; ++j) acc[i][j] = (f32x4){0.f, 0.f, 0.f, 0.f};

  for (int k0 = 0; k0 < K; k0 += 32) {
    int4 areg[2];
    int4 breg[TN / 64];
#pragma unroll
    for (int p = 0; p < 2; ++p) {
      int idx = p * 256 + tid, row = idx >> 2, kg = idx & 3;
      areg[p] = *(const int4*)(A + (size_t)(m0 + row) * K + k0 + kg * 8);
    }
#pragma unroll
    for (int p = 0; p < TN / 64; ++p) {
      int idx = p * 256 + tid, row = idx >> 2, kg = idx & 3;
      breg[p] = *(const int4*)(Bt + (size_t)(n0 + row) * K + k0 + kg * 8);
    }
    __syncthreads();
#pragma unroll
    for (int p = 0; p < 2; ++p) {
      int idx = p * 256 + tid, row = idx >> 2, kg = idx & 3;
      *(int4*)&As[row][kg * 8] = areg[p];
    }
#pragma unroll
    for (int p = 0; p < TN / 64; ++p) {
      int idx = p * 256 + tid, row = idx >> 2, kg = idx & 3;
      *(int4*)&Bs[row][kg * 8] = breg[p];
    }
    __syncthreads();
    bf16x8 af[4], bfr[WNF];
#pragma unroll
    for (int mm = 0; mm < 4; ++mm)
      af[mm] = *(const bf16x8*)&As[wm * 64 + mm * 16 + lrow][lk];
#pragma unroll
    for (int nn = 0; nn < WNF; ++nn)
      bfr[nn] = *(const bf16x8*)&Bs[wn * (WNF * 16) + nn * 16 + lrow][lk];
#pragma unroll
    for (int mm = 0; mm < 4; ++mm)
#pragma unroll
      for (int nn = 0; nn < WNF; ++nn)
        acc[mm][nn] = __builtin_amdgcn_mfma_f32_16x16x32_bf16(af[mm], bfr[nn], acc[mm][nn], 0, 0, 0);
  }
#pragma unroll
  for (int mm = 0; mm < 4; ++mm) {
#pragma unroll
    for (int nn = 0; nn < WNF; ++nn) {
#pragma unroll
      for (int r = 0; r < 4; ++r) {
        int row = m0 + wm * 64 + mm * 16 + (lane >> 4) * 4 + r;
        int col = n0 + wn * (WNF * 16) + nn * 16 + (lane & 15);
        float v = acc[mm][nn][r];
        if constexpr (EPI == 1) {
          if (col < actSplit) v = v * sigmoidf_(v);
        }
        if constexpr (EPI == 2) v += bias[col] + res[(size_t)row * N + col];
        if constexpr (EPI == 3) v += res[(size_t)row * N + col];
        C[(size_t)row * N + col] = v;
      }
    }
  }
}

// ---------------- swiglu: out = bf16(silu(gv[:, :2048]) * gv[:, 2048:]) ----------------
__global__ __launch_bounds__(256) void k_swiglu(const float* __restrict__ gv, bf16* __restrict__ out) {
  size_t idx = (size_t)blockIdx.x * 256 + threadIdx.x;  // over 2048*2048
  int m = (int)(idx >> 11), c = (int)(idx & 2047);
  float g = gv[(size_t)m * 4096 + c];
  float vv = gv[(size_t)m * 4096 + 2048 + c];
  out[idx] = __float2bfloat16(g * sigmoidf_(g) * vv);
}

// ---------------- sequential recurrence (rank-2 update form, barrier-free) ----------------
struct alignas(16) StepData {
  float k[16], q[16], bv[16];
  float v_i, bu_i;
  float beta, g, kq, kbv, bvq;
};

__device__ __forceinline__ void load_step(StepData& sd,
    const float* __restrict__ qkv, const float* __restrict__ buv,
    const float* __restrict__ betaA, const float* __restrict__ alphaA,
    const float* __restrict__ kqA, const float* __restrict__ kbvA,
    const float* __restrict__ bvqA, const int* __restrict__ mask,
    int b, int h, int s, int i, int j0) {
  int m = b * S_ + s;
  const float* qb = qkv + (size_t)m * 1536 + h * 64;
  const float* bb = buv + (size_t)m * 1024 + h * 64;
#pragma unroll
  for (int p = 0; p < 4; ++p) *(float4*)&sd.q[p * 4] = *(const float4*)(qb + j0 + p * 4);
#pragma unroll
  for (int p = 0; p < 4; ++p) *(float4*)&sd.k[p * 4] = *(const float4*)(qb + 512 + j0 + p * 4);
#pragma unroll
  for (int p = 0; p < 4; ++p) *(float4*)&sd.bv[p * 4] = *(const float4*)(bb + 512 + j0 + p * 4);
  sd.v_i = qb[1024 + i];
  sd.bu_i = bb[i];
  int mh = m * 8 + h;
  sd.beta = betaA[mh];
  sd.g = alphaA[mh] * (1.0f - (float)mask[m]);
  sd.kq = kqA[mh]; sd.kbv = kbvA[mh]; sd.bvq = bvqA[mh];
}

__device__ __forceinline__ void compute_step(float hs[16], const StepData& sd,
                                             float* __restrict__ attn_addr, bool writer) {
  float u = 0.f, w = 0.f;
#pragma unroll
  for (int jj = 0; jj < 16; ++jj) { u += hs[jj] * sd.k[jj]; w += hs[jj] * sd.q[jj]; }
  u += __shfl_xor(u, 1); u += __shfl_xor(u, 2);   // full row-dot across the 4 quarter-lanes
  w += __shfl_xor(w, 1); w += __shfl_xor(w, 2);
  float a_i = sd.beta * sd.v_i - sd.g * sd.beta * u;  // coeff of k[j]
  float c = sd.beta * sd.kbv;                         // bvp[j] = bv[j] - c*k[j]
#pragma unroll
  for (int jj = 0; jj < 16; ++jj) {
    float bvp = sd.bv[jj] - c * sd.k[jj];
    hs[jj] = sd.g * hs[jj] + a_i * sd.k[jj] + sd.bu_i * bvp;
  }
  if (writer) *attn_addr = sd.g * w + a_i * sd.kq + sd.bu_i * (sd.bvq - c * sd.kq);
}

__global__ __launch_bounds__(256) void k_recurrence(
    const float* __restrict__ qkv, const float* __restrict__ buv,
    const float* __restrict__ betaA, const float* __restrict__ alphaA,
    const float* __restrict__ kqA, const float* __restrict__ kbvA,
    const float* __restrict__ bvqA, const int* __restrict__ mask,
    const float* __restrict__ carry, float* __restrict__ attn, float* __restrict__ hsout) {
  int bh = blockIdx.x, b = bh >> 3, h = bh & 7;
  int tid = threadIdx.x, i = tid >> 2, quarter = tid & 3, j0 = quarter * 16;
  bool writer = (quarter == 0);
  float hs[16];
  const float* cr = carry + ((size_t)bh * 64 + i) * 64 + j0;
#pragma unroll
  for (int jj = 0; jj < 16; ++jj) hs[jj] = cr[jj];

  StepData A, Bst;
  load_step(A, qkv, buv, betaA, alphaA, kqA, kbvA, bvqA, mask, b, h, 0, i, j0);
  load_step(Bst, qkv, buv, betaA, alphaA, kqA, kbvA, bvqA, mask, b, h, 1, i, j0);
  for (int s = 0; s < S_; s += 2) {
    compute_step(hs, A, attn + ((size_t)(b * S_ + s) * 512 + h * 64 + i), writer);
    if (s + 2 < S_) load_step(A, qkv, buv, betaA, alphaA, kqA, kbvA, bvqA, mask, b, h, s + 2, i, j0);
    compute_step(hs, Bst, attn + ((size_t)(b * S_ + s + 1) * 512 + h * 64 + i), writer);
    if (s + 3 < S_) load_step(Bst, qkv, buv, betaA, alphaA, kqA, kbvA, bvqA, mask, b, h, s + 3, i, j0);
  }
  float* ho = hsout + ((size_t)bh * 64 + i) * 64 + j0;
#pragma unroll
  for (int jj = 0; jj < 16; ++jj) ho[jj] = hs[jj];
}

// ---------------- host ----------------
extern "C" void kernel_launch(void* const* d_in, const int* in_sizes, int n_in,
                              void* d_out, int out_size, void* d_ws, size_t ws_size,
                              hipStream_t stream) {
  const float* x      = (const float*)d_in[0];
  const int*   action = (const int*)d_in[1];
  const int*   mask   = (const int*)d_in[2];
  const float* carry  = (const float*)d_in[3];
  const float* n1s    = (const float*)d_in[4];
  const float* wq     = (const float*)d_in[5];
  const float* wk     = (const float*)d_in[6];
  const float* wv     = (const float*)d_in[7];
  const float* wbeta  = (const float*)d_in[8];
  const float* embed  = (const float*)d_in[9];
  const float* walpha = (const float*)d_in[10];
  const float* wbu    = (const float*)d_in[11];
  const float* wbv    = (const float*)d_in[12];
  const float* nas    = (const float*)d_in[13];
  const float* wout   = (const float*)d_in[14];
  const float* bout   = (const float*)d_in[15];
  const float* n2s    = (const float*)d_in[16];
  const float* wgate  = (const float*)d_in[17];
  const float* wval   = (const float*)d_in[18];
  const float* wffn   = (const float*)d_in[19];

  float* out_hs  = (float*)d_out;            // [2,8,64,64]
  float* out_ffn = (float*)d_out + 65536;    // [2,1024,512]

  char* p = (char*)d_ws;
  auto alloc = [&](size_t bytes) -> char* {
    char* r = p; p += (bytes + 255) & ~(size_t)255; return r;
  };
  bf16*  wqkvT = (bf16*)alloc((size_t)1536 * 512 * 2);
  bf16*  wbuvT = (bf16*)alloc((size_t)1024 * 512 * 2);
  bf16*  woutT = (bf16*)alloc((size_t)512 * 512 * 2);
  bf16*  wgvT  = (bf16*)alloc((size_t)4096 * 512 * 2);
  bf16*  wffnT = (bf16*)alloc((size_t)512 * 2048 * 2);
  float* hF    = (float*)alloc((size_t)M_ * 512 * 4);
  bf16*  hB    = (bf16*)alloc((size_t)M_ * 512 * 2);
  float* aeF   = (float*)alloc((size_t)M_ * 512 * 4);
  bf16*  aeB   = (bf16*)alloc((size_t)M_ * 512 * 2);
  float* qkvF  = (float*)alloc((size_t)M_ * 1536 * 4);
  float* buvF  = (float*)alloc((size_t)M_ * 1024 * 4);
  float* betaF = (float*)alloc((size_t)M_ * 8 * 4);
  float* alphaF= (float*)alloc((size_t)M_ * 8 * 4);
  float* kqF   = (float*)alloc((size_t)M_ * 8 * 4);
  float* kbvF  = (float*)alloc((size_t)M_ * 8 * 4);
  float* bvqF  = (float*)alloc((size_t)M_ * 8 * 4);
  float* attnF = (float*)alloc((size_t)M_ * 512 * 4);
  bf16*  attnB = (bf16*)alloc((size_t)M_ * 512 * 2);
  float* skipF = (float*)alloc((size_t)M_ * 512 * 4);
  bf16*  h2B   = (bf16*)alloc((size_t)M_ * 512 * 2);
  float* gvF   = (float*)alloc((size_t)M_ * 4096 * 4);
  bf16*  ffnB  = (bf16*)alloc((size_t)M_ * 2048 * 2);
  if ((size_t)(p - (char*)d_ws) > ws_size) return;  // workspace too small

  dim3 tb(32, 8);
  k_transpose_cast<<<dim3(16, 16), tb, 0, stream>>>(wq,   wqkvT,               512, 512);
  k_transpose_cast<<<dim3(16, 16), tb, 0, stream>>>(wk,   wqkvT + 512 * 512,   512, 512);
  k_transpose_cast<<<dim3(16, 16), tb, 0, stream>>>(wv,   wqkvT + 1024 * 512,  512, 512);
  k_transpose_cast<<<dim3(16, 16), tb, 0, stream>>>(wbu,  wbuvT,               512, 512);
  k_transpose_cast<<<dim3(16, 16), tb, 0, stream>>>(wbv,  wbuvT + 512 * 512,   512, 512);
  k_transpose_cast<<<dim3(16, 16), tb, 0, stream>>>(wout, woutT,               512, 512);
  k_transpose_cast<<<dim3(64, 16), tb, 0, stream>>>(wgate, wgvT,               512, 2048);
  k_transpose_cast<<<dim3(64, 16), tb, 0, stream>>>(wval,  wgvT + 2048 * 512,  512, 2048);
  k_transpose_cast<<<dim3(16, 64), tb, 0, stream>>>(wffn,  wffnT,              2048, 512);

  k_rmsnorm<<<M_, 256, 0, stream>>>(x, n1s, hF, hB);
  k_gather<<<M_, 256, 0, stream>>>(action, embed, aeF, aeB);

  k_gemm<1, 2><<<dim3(1536 / 64, 16), 256, 0, stream>>>(hB, wqkvT, qkvF, M_, 1536, 512, 1024, nullptr, nullptr);
  k_gemm<0, 2><<<dim3(1024 / 64, 16), 256, 0, stream>>>(aeB, wbuvT, buvF, M_, 1024, 512, 0, nullptr, nullptr);
  k_dot8_sigmoid<<<M_, 256, 0, stream>>>(hF, wbeta, betaF);
  k_dot8_sigmoid<<<M_, 256, 0, stream>>>(aeF, walpha, alphaF);
  k_qknorm_dots<<<M_ * 8, 64, 0, stream>>>(qkvF, buvF, kqF, kbvF, bvqF);

  k_recurrence<<<16, 256, 0, stream>>>(qkvF, buvF, betaF, alphaF, kqF, kbvF, bvqF,
                                       mask, carry, attnF, out_hs);

  k_rmsnorm<<<M_, 256, 0, stream>>>(attnF, nas, nullptr, attnB);
  k_gemm<2, 2><<<dim3(512 / 64, 16), 256, 0, stream>>>(attnB, woutT, skipF, M_, 512, 512, 0, bout, x);
  k_rmsnorm<<<M_, 256, 0, stream>>>(skipF, n2s, nullptr, h2B);
  k_gemm<0, 4><<<dim3(4096 / 128, 16), 256, 0, stream>>>(h2B, wgvT, gvF, M_, 4096, 512, 0, nullptr, nullptr);
  k_swiglu<<<(M_ * 2048) / 256, 256, 0, stream>>>(gvF, ffnB);
  k_gemm<3, 2><<<dim3(512 / 64, 16), 256, 0, stream>>>(ffnB, wffnT, out_ffn, M_, 512, 2048, 0, nullptr, skipF);
}